// Round 18
// baseline (282.295 us; speedup 1.0000x reference)
//
#include <hip/hip_runtime.h>
#include <math.h>

// ---------------- sizes ----------------
#define Bn 8
#define Wn 20
#define Mn 512
#define Fn 16
#define Hn 128

typedef __attribute__((ext_vector_type(8))) short short8;
typedef __attribute__((ext_vector_type(4))) float f32x4;
typedef unsigned short ushort_t;

__device__ __forceinline__ float sigmoidf_(float x) {
  float e = __expf(-x);
  return __builtin_amdgcn_rcpf(1.0f + e);
}
__device__ __forceinline__ float tanhf_(float x) {
  float xx = fminf(fmaxf(x, -15.f), 15.f);
  float e = __expf(2.f * xx);
  return (e - 1.f) * __builtin_amdgcn_rcpf(e + 1.f);
}
__device__ __forceinline__ float reluf_(float x) { return fmaxf(x, 0.f); }
__device__ __forceinline__ ushort_t bf16_rne(float v) {
  unsigned u = __float_as_uint(v);
  u += 0x7FFFu + ((u >> 16) & 1u);
  return (ushort_t)(u >> 16);
}
__device__ __forceinline__ float bf16_to_f(ushort_t b) {
  return __uint_as_float(((unsigned)b) << 16);
}
__device__ __forceinline__ void split8(const float v[8], short8& hi, short8& lo) {
#pragma unroll
  for (int j = 0; j < 8; ++j) {
    ushort_t h = bf16_rne(v[j]);
    hi[j] = (short)h;
    lo[j] = (short)bf16_rne(v[j] - bf16_to_f(h));
  }
}
__device__ __forceinline__ void load_gate_frags(
    const float* __restrict__ Whh, const float* __restrict__ Wih,
    int row, int quad, short8 fr[5][2]) {
  const float* wrow = Whh + (long)row * 128;
#pragma unroll
  for (int ks = 0; ks < 4; ++ks) {
    float v[8];
    float4 a4 = *(const float4*)&wrow[ks * 32 + quad * 8];
    float4 b4 = *(const float4*)&wrow[ks * 32 + quad * 8 + 4];
    v[0] = a4.x; v[1] = a4.y; v[2] = a4.z; v[3] = a4.w;
    v[4] = b4.x; v[5] = b4.y; v[6] = b4.z; v[7] = b4.w;
    split8(v, fr[ks][0], fr[ks][1]);
  }
  {
    float v[8] = {0.f, 0.f, 0.f, 0.f, 0.f, 0.f, 0.f, 0.f};
    if (quad < 2) {
      const float* xrow = Wih + (long)row * 16;
      float4 a4 = *(const float4*)&xrow[quad * 8];
      float4 b4 = *(const float4*)&xrow[quad * 8 + 4];
      v[0] = a4.x; v[1] = a4.y; v[2] = a4.z; v[3] = a4.w;
      v[4] = b4.x; v[5] = b4.y; v[6] = b4.z; v[7] = b4.w;
    }
    split8(v, fr[4][0], fr[4][1]);
  }
}

// ============ GRU: 8 seqs/block, 512 blocks => 2 chains/CU (latency hiding) ==
// Rows 8..15 of the MFMA A-tile stay zero; gate math guarded to quad<2.
#define LDK 168
#define HSZ (16 * LDK)
__global__ __launch_bounds__(512, 2) void gru_kernel(
    const float* __restrict__ X, const float* __restrict__ Whh,
    const float* __restrict__ Wih, const float* __restrict__ bih,
    const float* __restrict__ bhh, const float* __restrict__ W1,
    const float* __restrict__ W2, const float* __restrict__ b1,
    float* __restrict__ last_hid, float* __restrict__ p1,
    float* __restrict__ p2, float* __restrict__ ssq,
    float* __restrict__ d_out) {
  const int tid = threadIdx.x;
  const int wave = tid >> 6;
  const int lane = tid & 63;
  const int quad = lane >> 4;
  const int jl = lane & 15;
  const int j0 = wave * 16;
  const int blk = blockIdx.x;
  const int b = blk >> 6;
  const int m0 = (blk & 63) * 8;

  if (blk < 8) ssq[blk * 512 + tid] = 0.f;
  if (blk == 0 && tid == 0) d_out[0] = 0.f;

  __shared__ __align__(16) ushort_t smem_hs[4 * HSZ];  // hi0,hi1,lo0,lo1

  short8 frR[5][2], frZ[5][2], frN[5][2];
  load_gate_frags(Whh, Wih, wave * 16 + jl, quad, frR);
  load_gate_frags(Whh, Wih, 128 + wave * 16 + jl, quad, frZ);
  load_gate_frags(Whh, Wih, 256 + wave * 16 + jl, quad, frN);

  const float cr  = bih[j0 + jl] + bhh[j0 + jl];
  const float cz  = bih[128 + j0 + jl] + bhh[128 + j0 + jl];
  const float cnx = bih[256 + j0 + jl];
  const float cnh = bhh[256 + j0 + jl];

  for (int i = tid; i < 4 * HSZ; i += 512) smem_hs[i] = 0;

  const float* Xb = X + (long)b * (Wn * Mn * Fn) + (long)m0 * Fn;
  float x0 = 0.f;
  if (tid < 128) x0 = Xb[tid];          // 8 seqs x 16 feats
  __syncthreads();
  if (tid < 128) {
    int s = tid >> 4, f = tid & 15;
    ushort_t hb = bf16_rne(x0);
    smem_hs[0 * HSZ + s * LDK + 128 + f] = hb;
    smem_hs[2 * HSZ + s * LDK + 128 + f] = bf16_rne(x0 - bf16_to_f(hb));
  }
  __syncthreads();

  float hp[4] = {0.f, 0.f, 0.f, 0.f};

  for (int t = 0; t < Wn; ++t) {
    const int cur = t & 1, nxt = cur ^ 1;
    const int hiC = cur * HSZ, loC = (2 + cur) * HSZ;
    const int hiN = nxt * HSZ, loN = (2 + nxt) * HSZ;
    float xpre = 0.f;
    if (tid < 128 && t < Wn - 1) xpre = Xb[(long)(t + 1) * (Mn * Fn) + tid];

    f32x4 aR[2], aZ[2], aHN[2], aXN;
    aR[0] = aR[1] = aZ[0] = aZ[1] = aHN[0] = aHN[1] = aXN = (f32x4){0.f, 0.f, 0.f, 0.f};
#pragma unroll
    for (int ks = 0; ks < 5; ++ks) {
      const int p = ks & 1;
      short8 ah = *(const short8*)&smem_hs[hiC + jl * LDK + ks * 32 + quad * 8];
      short8 al = *(const short8*)&smem_hs[loC + jl * LDK + ks * 32 + quad * 8];
      aR[p] = __builtin_amdgcn_mfma_f32_16x16x32_bf16(ah, frR[ks][0], aR[p], 0, 0, 0);
      aR[p] = __builtin_amdgcn_mfma_f32_16x16x32_bf16(ah, frR[ks][1], aR[p], 0, 0, 0);
      aR[p] = __builtin_amdgcn_mfma_f32_16x16x32_bf16(al, frR[ks][0], aR[p], 0, 0, 0);
      aZ[p] = __builtin_amdgcn_mfma_f32_16x16x32_bf16(ah, frZ[ks][0], aZ[p], 0, 0, 0);
      aZ[p] = __builtin_amdgcn_mfma_f32_16x16x32_bf16(ah, frZ[ks][1], aZ[p], 0, 0, 0);
      aZ[p] = __builtin_amdgcn_mfma_f32_16x16x32_bf16(al, frZ[ks][0], aZ[p], 0, 0, 0);
      if (ks < 4) {
        aHN[p] = __builtin_amdgcn_mfma_f32_16x16x32_bf16(ah, frN[ks][0], aHN[p], 0, 0, 0);
        aHN[p] = __builtin_amdgcn_mfma_f32_16x16x32_bf16(ah, frN[ks][1], aHN[p], 0, 0, 0);
        aHN[p] = __builtin_amdgcn_mfma_f32_16x16x32_bf16(al, frN[ks][0], aHN[p], 0, 0, 0);
      } else {
        aXN = __builtin_amdgcn_mfma_f32_16x16x32_bf16(ah, frN[4][0], aXN, 0, 0, 0);
        aXN = __builtin_amdgcn_mfma_f32_16x16x32_bf16(ah, frN[4][1], aXN, 0, 0, 0);
        aXN = __builtin_amdgcn_mfma_f32_16x16x32_bf16(al, frN[4][0], aXN, 0, 0, 0);
      }
    }

    if (quad < 2) {                      // seqs quad*4+reg in 0..7
#pragma unroll
      for (int reg = 0; reg < 4; ++reg) {
        float r = sigmoidf_(aR[0][reg] + aR[1][reg] + cr);
        float z = sigmoidf_(aZ[0][reg] + aZ[1][reg] + cz);
        float n = tanhf_(aXN[reg] + cnx + r * (aHN[0][reg] + aHN[1][reg] + cnh));
        float h = (1.f - z) * n + z * hp[reg];
        hp[reg] = h;
        int s = quad * 4 + reg;
        ushort_t hb = bf16_rne(h);
        smem_hs[hiN + s * LDK + j0 + jl] = hb;
        smem_hs[loN + s * LDK + j0 + jl] = bf16_rne(h - bf16_to_f(hb));
      }
    }
    if (tid < 128 && t < Wn - 1) {
      int s = tid >> 4, f = tid & 15;
      ushort_t hb = bf16_rne(xpre);
      smem_hs[hiN + s * LDK + 128 + f] = hb;
      smem_hs[loN + s * LDK + 128 + f] = bf16_rne(xpre - bf16_to_f(hb));
    }
    __syncthreads();   // single barrier per step
  }

  float* hs_f = (float*)smem_hs;          // 8 x 132 floats used
  if (quad < 2) {
#pragma unroll
    for (int reg = 0; reg < 4; ++reg) {
      int s = quad * 4 + reg;
      float h = hp[reg];
      last_hid[(long)(blk * 8 + s) * Hn + j0 + jl] = h;
      hs_f[s * 132 + j0 + jl] = h;
    }
  }
  __syncthreads();
  {
    int k = tid & 63;
    int part = (tid >> 6) & 1;
    int sg = tid >> 7;                    // 0..3 -> rows sg*2, sg*2+1
    const float* Wp = part ? W2 : W1;
    float a[2];
    float init = part ? 0.f : b1[k];
    a[0] = a[1] = init;
    for (int h = 0; h < 128; h += 4) {
      float4 w = *(const float4*)&Wp[k * 128 + h];
#pragma unroll
      for (int rr = 0; rr < 2; ++rr) {
        float4 q = *(const float4*)&hs_f[(sg * 2 + rr) * 132 + h];
        a[rr] += q.x * w.x + q.y * w.y + q.z * w.z + q.w * w.w;
      }
    }
    float* outp = part ? p2 : p1;
#pragma unroll
    for (int rr = 0; rr < 2; ++rr)
      outp[(long)(blk * 8 + sg * 2 + rr) * 64 + k] = a[rr];
  }
}

// ============ mid: conv_t1 + 64x64-tile amx (factored exp) + WbT =============
__global__ __launch_bounds__(256, 2) void mid_kernel(
    const float* __restrict__ X, const float* __restrict__ conv_w,
    const float* __restrict__ conv_b, const float* __restrict__ convl_w,
    const float* __restrict__ convl_b, const float* __restrict__ gc1_W,
    const float* __restrict__ p1, const float* __restrict__ p2,
    const float* __restrict__ V, const float* __restrict__ bv,
    const float* __restrict__ Wb, ushort_t* __restrict__ t1T_hi,
    ushort_t* __restrict__ t1T_lo, ushort_t* __restrict__ WbT_hi,
    ushort_t* __restrict__ WbT_lo, float* __restrict__ amx,
    float* __restrict__ ssq) {
  int tid = threadIdx.x, blk = blockIdx.x;
  __shared__ __align__(16) char sm[73984];

  // ---- phase A: conv + t1 (8 nodes/block over 512 blocks) ----
  {
    float* xs  = (float*)sm;            // 2560 f
    float* cw  = (float*)(sm + 10240);  // 3200 f
    float* clw = (float*)(sm + 23040);  // 1600 f
    float* rs  = (float*)(sm + 29440);  // 8 x 32 f
    int n0 = blk * 8, b = n0 >> 9, m0 = n0 & 511;
    for (int idx = tid; idx < 3200; idx += 256) cw[idx] = conv_w[idx];
    for (int idx = tid; idx < 1600; idx += 256) clw[idx] = convl_w[idx];
    if (tid < 128) {
      for (int w = 0; w < 20; ++w)
        xs[tid * 20 + w] = X[((long)(b * 20 + w) * 512 + m0) * 16 + tid];
    }
    __syncthreads();
    if (tid < 80) {
      int s = tid / 10, k = tid % 10;
      float a0 = conv_b[k];
      float l0 = convl_b[k], l1 = convl_b[k];
      for (int f = 0; f < 16; ++f) {
        const float* xp = &xs[(s * 16 + f) * 20];
#pragma unroll
        for (int w = 0; w < 20; ++w) a0 = fmaf(xp[w], cw[k * 320 + f * 20 + w], a0);
#pragma unroll
        for (int q = 0; q < 10; ++q) {
          float wv = clw[k * 160 + f * 10 + q];
          l0 = fmaf(xp[2 * q], wv, l0);
          l1 = fmaf(xp[2 * q + 1], wv, l1);
        }
      }
      rs[s * 32 + k * 3 + 0] = reluf_(a0);
      rs[s * 32 + k * 3 + 1] = reluf_(l0);
      rs[s * 32 + k * 3 + 2] = reluf_(l1);
    }
    __syncthreads();
    if (tid < 128) {
      float w[30];
#pragma unroll
      for (int q = 0; q < 30; ++q) w[q] = gc1_W[q * 128 + tid];
      long base = ((long)b * 128 + tid) * 512 + m0;
#pragma unroll
      for (int s = 0; s < 8; ++s) {
        float a = 0.f;
#pragma unroll
        for (int q = 0; q < 30; ++q) a = fmaf(rs[s * 32 + q], w[q], a);
        ushort_t hb = bf16_rne(a);
        t1T_hi[base + s] = hb;
        t1T_lo[base + s] = bf16_rne(a - bf16_to_f(hb));
      }
    }
  }
  __syncthreads();

  // ---- phase B: amx 64x64 tile per block; exp factored out of inner loop ----
  {
    float* p1s  = (float*)sm;            // 64 x 68
    float* e1s  = (float*)(sm + 17408);  // 64 x 68
    float* p2s  = (float*)(sm + 34816);  // 64 x 68
    float* e2s  = (float*)(sm + 52224);  // 64 x 68
    float* cred = (float*)(sm + 69632);  // 16 x 68
    float4 vreg[16];
#pragma unroll
    for (int q = 0; q < 16; ++q) vreg[q] = *(const float4*)&V[q * 4];
    float bvv = bv[0];
    int bz = blk >> 6, i0 = ((blk >> 3) & 7) * 64, j0 = (blk & 7) * 64;
    int r0 = tid >> 4, c0 = tid & 15;

#pragma unroll
    for (int l = 0; l < 4; ++l) {
      int e = l * 1024 + tid * 4;
      int r = e >> 6, c = e & 63;
      float4 v1 = *(const float4*)&p1[(long)(bz * 512 + j0 + r) * 64 + c];
      float4 v2 = *(const float4*)&p2[(long)(bz * 512 + i0 + r) * 64 + c];
      *(float4*)&p1s[r * 68 + c] = v1;
      *(float4*)&p2s[r * 68 + c] = v2;
      float4 x1, x2;
      x1.x = __expf(v1.x); x1.y = __expf(v1.y); x1.z = __expf(v1.z); x1.w = __expf(v1.w);
      x2.x = __expf(v2.x); x2.y = __expf(v2.y); x2.z = __expf(v2.z); x2.w = __expf(v2.w);
      *(float4*)&e1s[r * 68 + c] = x1;
      *(float4*)&e2s[r * 68 + c] = x2;
    }
    __syncthreads();

    float acc[4][4] = {};
    for (int kq = 0; kq < 16; ++kq) {
      float4 pa[4], pb[4], ea[4], eb[4];
#pragma unroll
      for (int q = 0; q < 4; ++q) {
        pa[q] = *(const float4*)&p1s[(c0 + q * 16) * 68 + kq * 4];
        ea[q] = *(const float4*)&e1s[(c0 + q * 16) * 68 + kq * 4];
        pb[q] = *(const float4*)&p2s[(r0 + q * 16) * 68 + kq * 4];
        eb[q] = *(const float4*)&e2s[(r0 + q * 16) * 68 + kq * 4];
      }
      float4 vv = vreg[kq];
#pragma unroll
      for (int ri = 0; ri < 4; ++ri)
#pragma unroll
        for (int ci = 0; ci < 4; ++ci) {
          float s0 = pa[ci].x + pb[ri].x;
          float m0v = fmaf(ea[ci].x, eb[ri].x, -1.f);
          acc[ri][ci] = fmaf(s0 > 0.f ? s0 : m0v, vv.x, acc[ri][ci]);
          float s1 = pa[ci].y + pb[ri].y;
          float m1v = fmaf(ea[ci].y, eb[ri].y, -1.f);
          acc[ri][ci] = fmaf(s1 > 0.f ? s1 : m1v, vv.y, acc[ri][ci]);
          float s2v = pa[ci].z + pb[ri].z;
          float m2v = fmaf(ea[ci].z, eb[ri].z, -1.f);
          acc[ri][ci] = fmaf(s2v > 0.f ? s2v : m2v, vv.z, acc[ri][ci]);
          float s3 = pa[ci].w + pb[ri].w;
          float m3v = fmaf(ea[ci].w, eb[ri].w, -1.f);
          acc[ri][ci] = fmaf(s3 > 0.f ? s3 : m3v, vv.w, acc[ri][ci]);
        }
    }
    __syncthreads();
    float* outs = p1s;
    float s2[4] = {0.f, 0.f, 0.f, 0.f};
#pragma unroll
    for (int ri = 0; ri < 4; ++ri)
#pragma unroll
      for (int ci = 0; ci < 4; ++ci) {
        float v = acc[ri][ci] + bvv;
        outs[(r0 + ri * 16) * 68 + c0 + ci * 16] = v;
        s2[ci] += v * v;
      }
#pragma unroll
    for (int ci = 0; ci < 4; ++ci) cred[r0 * 68 + c0 + ci * 16] = s2[ci];
    __syncthreads();
#pragma unroll
    for (int l = 0; l < 4; ++l) {
      int e = l * 1024 + tid * 4;
      int r = e >> 6, c = e & 63;
      *(float4*)&amx[((long)(bz * 512 + i0 + r)) * 512 + j0 + c] =
          *(const float4*)&outs[r * 68 + c];
    }
    if (tid < 64) {
      float s = 0.f;
#pragma unroll
      for (int p = 0; p < 16; ++p) s += cred[p * 68 + tid];
      atomicAdd(&ssq[bz * 512 + j0 + tid], s);
    }
  }

  // ---- phase C: WbT transpose+split (blocks 0..63) ----
  if (blk < 64) {
    __syncthreads();
    float* wt = (float*)sm;   // 64 x 65
    int k0 = (blk >> 3) * 64, j0w = (blk & 7) * 64;
    for (int idx = tid; idx < 4096; idx += 256) {
      int r = idx >> 6, c = idx & 63;
      wt[r * 65 + c] = Wb[(long)(k0 + r) * 512 + j0w + c];
    }
    __syncthreads();
    for (int idx = tid; idx < 4096; idx += 256) {
      int r = idx >> 6, c = idx & 63;
      float v = wt[c * 65 + r];
      ushort_t hb = bf16_rne(v);
      WbT_hi[(long)(j0w + r) * 512 + k0 + c] = hb;
      WbT_lo[(long)(j0w + r) * 512 + k0 + c] = bf16_rne(v - bf16_to_f(hb));
    }
  }
}

// ---- gemm_cA via split-bf16 MFMA: 64x64 tiles, 512 blocks x 4 waves ----
#define CPK 40
__global__ __launch_bounds__(256, 2) void gemm_cA(
    const float* __restrict__ amx, const ushort_t* __restrict__ WbT_hi,
    const ushort_t* __restrict__ WbT_lo, const float* __restrict__ adj,
    const float* __restrict__ wb, const float* __restrict__ ssq,
    float* __restrict__ A) {
  const int bz = blockIdx.z;
  const int i0 = blockIdx.y * 64;
  const int j0 = blockIdx.x * 64;
  const int tid = threadIdx.x;
  const int wave = tid >> 6;
  const int lane = tid & 63;
  const int quad = lane >> 4, jl = lane & 15;
  const int wm = (wave & 1) * 32, wn = (wave >> 1) * 32;

  __shared__ __align__(16) ushort_t Ahi[64][CPK];
  __shared__ __align__(16) ushort_t Alo[64][CPK];
  __shared__ __align__(16) ushort_t Bhi[64][CPK];
  __shared__ __align__(16) ushort_t Blo[64][CPK];
  __shared__ float rs_s[512];

  const float* Abase = amx + (long)bz * 262144;
  const float* sb = ssq + bz * 512;
  for (int i = tid; i < 512; i += 256)
    rs_s[i] = __builtin_amdgcn_rcpf(fmaxf(sqrtf(sb[i]), 1e-12f));

  f32x4 acc[2][2];
#pragma unroll
  for (int a = 0; a < 2; ++a)
#pragma unroll
    for (int c = 0; c < 2; ++c) acc[a][c] = (f32x4){0.f, 0.f, 0.f, 0.f};

  for (int kk0 = 0; kk0 < 512; kk0 += 32) {
    __syncthreads();
#pragma unroll
    for (int l = 0; l < 2; ++l) {
      int e = l * 1024 + tid * 4;
      int r = e >> 5, kq = e & 31;
      float4 v = *(const float4*)&Abase[(long)(i0 + r) * 512 + kk0 + kq];
      float4 sc = *(const float4*)&rs_s[kk0 + kq];
      float vv[4] = {v.x * sc.x, v.y * sc.y, v.z * sc.z, v.w * sc.w};
#pragma unroll
      for (int q = 0; q < 4; ++q) {
        ushort_t hb = bf16_rne(vv[q]);
        Ahi[r][kq + q] = hb;
        Alo[r][kq + q] = bf16_rne(vv[q] - bf16_to_f(hb));
      }
    }
    {
      int r = tid >> 2, kc = (tid & 3) * 8;
      *(uint4*)&Bhi[r][kc] = *(const uint4*)&WbT_hi[(long)(j0 + r) * 512 + kk0 + kc];
      *(uint4*)&Blo[r][kc] = *(const uint4*)&WbT_lo[(long)(j0 + r) * 512 + kk0 + kc];
    }
    __syncthreads();
    short8 ah[2], al[2], bh[2], bl[2];
#pragma unroll
    for (int tm = 0; tm < 2; ++tm) {
      ah[tm] = *(const short8*)&Ahi[wm + tm * 16 + jl][quad * 8];
      al[tm] = *(const short8*)&Alo[wm + tm * 16 + jl][quad * 8];
    }
#pragma unroll
    for (int tn = 0; tn < 2; ++tn) {
      bh[tn] = *(const short8*)&Bhi[wn + tn * 16 + jl][quad * 8];
      bl[tn] = *(const short8*)&Blo[wn + tn * 16 + jl][quad * 8];
    }
#pragma unroll
    for (int tm = 0; tm < 2; ++tm)
#pragma unroll
      for (int tn = 0; tn < 2; ++tn) {
        acc[tm][tn] = __builtin_amdgcn_mfma_f32_16x16x32_bf16(ah[tm], bh[tn], acc[tm][tn], 0, 0, 0);
        acc[tm][tn] = __builtin_amdgcn_mfma_f32_16x16x32_bf16(ah[tm], bl[tn], acc[tm][tn], 0, 0, 0);
        acc[tm][tn] = __builtin_amdgcn_mfma_f32_16x16x32_bf16(al[tm], bh[tn], acc[tm][tn], 0, 0, 0);
      }
  }

  const float wbv = wb[0];
#pragma unroll
  for (int tn = 0; tn < 2; ++tn) {
    int j = j0 + wn + tn * 16 + jl;
    float sj = rs_s[j];
#pragma unroll
    for (int tm = 0; tm < 2; ++tm) {
#pragma unroll
      for (int reg = 0; reg < 4; ++reg) {
        int i = i0 + wm + tm * 16 + quad * 4 + reg;
        long ofs = (long)bz * 262144 + (long)i * 512 + j;
        float c = sigmoidf_(acc[tm][tn][reg] + wbv);
        float am = Abase[(long)i * 512 + j] * sj;
        float ad = adj[(long)i * 512 + j];
        A[ofs] = ad * c + am * (1.f - c);
      }
    }
  }
}

// ---------------- gemm_h1 + fused t2: 512 threads, 8 waves ----
__global__ __launch_bounds__(512, 1) void gemm_h1t2(
    const float* __restrict__ A, const ushort_t* __restrict__ t1T_hi,
    const ushort_t* __restrict__ t1T_lo, const float* __restrict__ gc1_b,
    const float* __restrict__ gc2_W, float* __restrict__ t2) {
  const int bz = blockIdx.y;
  const int i0 = blockIdx.x * 16;
  const int tid = threadIdx.x;
  const int wave = tid >> 6;
  const int lane = tid & 63;
  const int quad = lane >> 4, jl = lane & 15;

  __shared__ __align__(16) ushort_t Ahi[16][CPK];
  __shared__ __align__(16) ushort_t Alo[16][CPK];
  __shared__ __align__(16) ushort_t Bhi[128][CPK];
  __shared__ __align__(16) ushort_t Blo[128][CPK];
  __shared__ float h1s[16][132];
  __shared__ float gw[1280];

  const float* Ab = A + (long)bz * 262144;
  for (int idx = tid; idx < 1280; idx += 512) gw[idx] = gc2_W[idx];

  f32x4 acc = {0.f, 0.f, 0.f, 0.f};

  for (int kk0 = 0; kk0 < 512; kk0 += 32) {
    __syncthreads();
    {
      int r = tid >> 5, kq = tid & 31;
      float v = Ab[(long)(i0 + r) * 512 + kk0 + kq];
      ushort_t hb = bf16_rne(v);
      Ahi[r][kq] = hb;
      Alo[r][kq] = bf16_rne(v - bf16_to_f(hb));
    }
    {
      int r = tid >> 2, kc = (tid & 3) * 8;
      *(uint4*)&Bhi[r][kc] = *(const uint4*)&t1T_hi[((long)bz * 128 + r) * 512 + kk0 + kc];
      *(uint4*)&Blo[r][kc] = *(const uint4*)&t1T_lo[((long)bz * 128 + r) * 512 + kk0 + kc];
    }
    __syncthreads();
    short8 ah = *(const short8*)&Ahi[jl][quad * 8];
    short8 al = *(const short8*)&Alo[jl][quad * 8];
    short8 bh = *(const short8*)&Bhi[wave * 16 + jl][quad * 8];
    short8 bl = *(const short8*)&Blo[wave * 16 + jl][quad * 8];
    acc = __builtin_amdgcn_mfma_f32_16x16x32_bf16(ah, bh, acc, 0, 0, 0);
    acc = __builtin_amdgcn_mfma_f32_16x16x32_bf16(ah, bl, acc, 0, 0, 0);
    acc = __builtin_amdgcn_mfma_f32_16x16x32_bf16(al, bh, acc, 0, 0, 0);
  }
  __syncthreads();
  {
    int n = wave * 16 + jl;
    float bb = gc1_b[n];
#pragma unroll
    for (int reg = 0; reg < 4; ++reg) {
      int r = quad * 4 + reg;
      h1s[r][n] = reluf_(acc[reg] + bb);
    }
  }
  __syncthreads();
  if (tid < 160) {
    int r = tid / 10, c = tid % 10;
    float a = 0.f;
#pragma unroll 4
    for (int k = 0; k < 128; ++k) a = fmaf(h1s[r][k], gw[k * 10 + c], a);
    t2[((long)bz * 512 + i0 + r) * 10 + c] = a;
  }
}

// ---------------- spat+readout: BM=8, 512 blocks ----
__global__ __launch_bounds__(256) void spat_readout(
    const float* __restrict__ A, const float* __restrict__ t2,
    const float* __restrict__ gc2_b, const float* __restrict__ last_hid,
    const float* __restrict__ out_W, const float* __restrict__ out_b,
    const float* __restrict__ Y, float* __restrict__ d_out) {
  int tid = threadIdx.x;
  int bz = blockIdx.y;
  int i0 = blockIdx.x * 8;
  __shared__ float t2s[5120];
  __shared__ float wS[138];
  __shared__ float osps[8][12];
  for (int idx = tid; idx < 5120; idx += 256) t2s[idx] = t2[(long)bz * 5120 + idx];
  for (int idx = tid; idx < 138; idx += 256) wS[idx] = out_W[idx];
  __syncthreads();
  int r = tid >> 5, sk = tid & 31;
  const float* Arow = A + (long)bz * 262144 + (long)(i0 + r) * 512;
  float acc[10] = {0, 0, 0, 0, 0, 0, 0, 0, 0, 0};
  for (int k = sk; k < 512; k += 32) {
    float av = Arow[k];
    const float* tp = &t2s[k * 10];
#pragma unroll
    for (int c = 0; c < 10; ++c) acc[c] = fmaf(av, tp[c], acc[c]);
  }
#pragma unroll
  for (int off = 16; off; off >>= 1)
#pragma unroll
    for (int c = 0; c < 10; ++c) acc[c] += __shfl_xor(acc[c], off);
  if (sk == 0) {
#pragma unroll
    for (int c = 0; c < 10; ++c) osps[r][c] = reluf_(acc[c] + gc2_b[c]);
  }
  __syncthreads();
  float l = 0.f;
  if (tid < 8) {
    int gid = bz * 512 + i0 + tid;
    float y = out_b[0];
#pragma unroll
    for (int k = 0; k < 10; ++k) y = fmaf(osps[tid][k], wS[k], y);
    const float* hp = &last_hid[(long)gid * 128];
    for (int h = 0; h < 128; h += 4) {
      float4 hv = *(const float4*)&hp[h];
      y = fmaf(hv.x, wS[10 + h + 0], y);
      y = fmaf(hv.y, wS[10 + h + 1], y);
      y = fmaf(hv.z, wS[10 + h + 2], y);
      y = fmaf(hv.w, wS[10 + h + 3], y);
    }
    d_out[1 + gid] = sigmoidf_(y);
    l = fmaxf(y, 0.f) + log1pf(__expf(-fabsf(y))) - Y[gid] * y;
  }
  if (tid < 64) {
#pragma unroll
    for (int off = 4; off; off >>= 1) l += __shfl_down(l, off);
    if (tid == 0) atomicAdd(d_out, l * (1.0f / 4096.f));
  }
}

// ---------------- launcher (5 dispatches) ----------------
extern "C" void kernel_launch(void* const* d_in, const int* in_sizes, int n_in,
                              void* d_out, int out_size, void* d_ws, size_t ws_size,
                              hipStream_t stream) {
  const float* X       = (const float*)d_in[0];
  const float* Y       = (const float*)d_in[1];
  const float* adj     = (const float*)d_in[2];
  const float* V       = (const float*)d_in[3];
  const float* bv      = (const float*)d_in[4];
  const float* W1      = (const float*)d_in[5];
  const float* b1      = (const float*)d_in[6];
  const float* W2      = (const float*)d_in[7];
  const float* Wb      = (const float*)d_in[8];
  const float* wb      = (const float*)d_in[9];
  const float* conv_w  = (const float*)d_in[10];
  const float* conv_b  = (const float*)d_in[11];
  const float* convl_w = (const float*)d_in[12];
  const float* convl_b = (const float*)d_in[13];
  const float* gWih    = (const float*)d_in[14];
  const float* gWhh    = (const float*)d_in[15];
  const float* gbih    = (const float*)d_in[16];
  const float* gbhh    = (const float*)d_in[17];
  const float* gc1_W   = (const float*)d_in[18];
  const float* gc1_b   = (const float*)d_in[19];
  const float* gc2_W   = (const float*)d_in[20];
  const float* gc2_b   = (const float*)d_in[21];
  const float* out_W   = (const float*)d_in[22];
  const float* out_b   = (const float*)d_in[23];
  float* out = (float*)d_out;

  float* ws = (float*)d_ws;
  float* lhid  = ws; ws += 524288;
  float* p1    = ws; ws += 262144;
  float* p2    = ws; ws += 262144;
  float* amx   = ws; ws += 2097152;
  float* ssq   = ws; ws += 4096;
  float* Abuf  = ws; ws += 2097152;
  float* t2    = ws; ws += 40960;
  float* WbTf  = ws; ws += 262144;   // 2 x 262144 ushorts
  float* t1Tf  = ws; ws += 524288;   // 2 x 524288 ushorts
  if (ws_size < (size_t)(ws - (float*)d_ws) * sizeof(float)) return;
  ushort_t* WbT_hi = (ushort_t*)WbTf;
  ushort_t* WbT_lo = WbT_hi + 262144;
  ushort_t* t1T_hi = (ushort_t*)t1Tf;
  ushort_t* t1T_lo = t1T_hi + 524288;

  gru_kernel<<<512, 512, 0, stream>>>(X, gWhh, gWih, gbih, gbhh, W1, W2, b1,
                                      lhid, p1, p2, ssq, out);
  mid_kernel<<<512, 256, 0, stream>>>(X, conv_w, conv_b, convl_w, convl_b,
                                      gc1_W, p1, p2, V, bv, Wb,
                                      t1T_hi, t1T_lo, WbT_hi, WbT_lo, amx, ssq);
  gemm_cA<<<dim3(8, 8, 8), 256, 0, stream>>>(amx, WbT_hi, WbT_lo, adj, wb,
                                             ssq, Abuf);
  gemm_h1t2<<<dim3(32, 8), 512, 0, stream>>>(Abuf, t1T_hi, t1T_lo, gc1_b,
                                             gc2_W, t2);
  spat_readout<<<dim3(64, 8), 256, 0, stream>>>(Abuf, t2, gc2_b, lhid,
                                                out_W, out_b, Y, out);
}

// Round 19
// 240.546 us; speedup vs baseline: 1.1736x; 1.1736x over previous
//
#include <hip/hip_runtime.h>
#include <math.h>

// ---------------- sizes ----------------
#define Bn 8
#define Wn 20
#define Mn 512
#define Fn 16
#define Hn 128

typedef __attribute__((ext_vector_type(8))) short short8;
typedef __attribute__((ext_vector_type(4))) float f32x4;
typedef unsigned short ushort_t;

__device__ __forceinline__ float sigmoidf_(float x) {
  float e = __expf(-x);
  return __builtin_amdgcn_rcpf(1.0f + e);
}
__device__ __forceinline__ float tanhf_(float x) {
  float xx = fminf(fmaxf(x, -15.f), 15.f);
  float e = __expf(2.f * xx);
  return (e - 1.f) * __builtin_amdgcn_rcpf(e + 1.f);
}
__device__ __forceinline__ float reluf_(float x) { return fmaxf(x, 0.f); }
__device__ __forceinline__ ushort_t bf16_rne(float v) {
  unsigned u = __float_as_uint(v);
  u += 0x7FFFu + ((u >> 16) & 1u);
  return (ushort_t)(u >> 16);
}
__device__ __forceinline__ float bf16_to_f(ushort_t b) {
  return __uint_as_float(((unsigned)b) << 16);
}
__device__ __forceinline__ void split8(const float v[8], short8& hi, short8& lo) {
#pragma unroll
  for (int j = 0; j < 8; ++j) {
    ushort_t h = bf16_rne(v[j]);
    hi[j] = (short)h;
    lo[j] = (short)bf16_rne(v[j] - bf16_to_f(h));
  }
}
__device__ __forceinline__ void load_gate_frags(
    const float* __restrict__ Whh, const float* __restrict__ Wih,
    int row, int quad, short8 fr[5][2]) {
  const float* wrow = Whh + (long)row * 128;
#pragma unroll
  for (int ks = 0; ks < 4; ++ks) {
    float v[8];
    float4 a4 = *(const float4*)&wrow[ks * 32 + quad * 8];
    float4 b4 = *(const float4*)&wrow[ks * 32 + quad * 8 + 4];
    v[0] = a4.x; v[1] = a4.y; v[2] = a4.z; v[3] = a4.w;
    v[4] = b4.x; v[5] = b4.y; v[6] = b4.z; v[7] = b4.w;
    split8(v, fr[ks][0], fr[ks][1]);
  }
  {
    float v[8] = {0.f, 0.f, 0.f, 0.f, 0.f, 0.f, 0.f, 0.f};
    if (quad < 2) {
      const float* xrow = Wih + (long)row * 16;
      float4 a4 = *(const float4*)&xrow[quad * 8];
      float4 b4 = *(const float4*)&xrow[quad * 8 + 4];
      v[0] = a4.x; v[1] = a4.y; v[2] = a4.z; v[3] = a4.w;
      v[4] = b4.x; v[5] = b4.y; v[6] = b4.z; v[7] = b4.w;
    }
    split8(v, fr[4][0], fr[4][1]);
  }
}

// ============ GRU: direct-from-global weight fragments, split-bf16 MFMA ======
// (round-17 configuration — best measured; 16 seqs/block, 256 blocks)
#define LDK 168
#define HSZ (16 * LDK)
__global__ __launch_bounds__(512, 1) void gru_kernel(
    const float* __restrict__ X, const float* __restrict__ Whh,
    const float* __restrict__ Wih, const float* __restrict__ bih,
    const float* __restrict__ bhh, const float* __restrict__ W1,
    const float* __restrict__ W2, const float* __restrict__ b1,
    float* __restrict__ last_hid, float* __restrict__ p1,
    float* __restrict__ p2, float* __restrict__ ssq,
    float* __restrict__ d_out) {
  const int tid = threadIdx.x;
  const int wave = tid >> 6;
  const int lane = tid & 63;
  const int quad = lane >> 4;
  const int jl = lane & 15;
  const int j0 = wave * 16;
  const int blk = blockIdx.x;
  const int b = blk >> 5;
  const int m0 = (blk & 31) * 16;

  if (blk < 8) ssq[blk * 512 + tid] = 0.f;
  if (blk == 0 && tid == 0) d_out[0] = 0.f;

  __shared__ __align__(16) ushort_t smem_hs[4 * HSZ];  // hi0,hi1,lo0,lo1

  short8 frR[5][2], frZ[5][2], frN[5][2];
  load_gate_frags(Whh, Wih, wave * 16 + jl, quad, frR);
  load_gate_frags(Whh, Wih, 128 + wave * 16 + jl, quad, frZ);
  load_gate_frags(Whh, Wih, 256 + wave * 16 + jl, quad, frN);

  const float cr  = bih[j0 + jl] + bhh[j0 + jl];
  const float cz  = bih[128 + j0 + jl] + bhh[128 + j0 + jl];
  const float cnx = bih[256 + j0 + jl];
  const float cnh = bhh[256 + j0 + jl];

  for (int i = tid; i < 4 * HSZ; i += 512) smem_hs[i] = 0;

  const float* Xb = X + (long)b * (Wn * Mn * Fn) + (long)m0 * Fn;
  float x0 = 0.f;
  if (tid < 256) x0 = Xb[tid];
  __syncthreads();
  if (tid < 256) {
    int s = tid >> 4, f = tid & 15;
    ushort_t hb = bf16_rne(x0);
    smem_hs[0 * HSZ + s * LDK + 128 + f] = hb;
    smem_hs[2 * HSZ + s * LDK + 128 + f] = bf16_rne(x0 - bf16_to_f(hb));
  }
  __syncthreads();

  float hp[4] = {0.f, 0.f, 0.f, 0.f};

  for (int t = 0; t < Wn; ++t) {
    const int cur = t & 1, nxt = cur ^ 1;
    const int hiC = cur * HSZ, loC = (2 + cur) * HSZ;
    const int hiN = nxt * HSZ, loN = (2 + nxt) * HSZ;
    float xpre = 0.f;
    if (tid < 256 && t < Wn - 1) xpre = Xb[(long)(t + 1) * (Mn * Fn) + tid];

    f32x4 aR[2], aZ[2], aHN[2], aXN;
    aR[0] = aR[1] = aZ[0] = aZ[1] = aHN[0] = aHN[1] = aXN = (f32x4){0.f, 0.f, 0.f, 0.f};
#pragma unroll
    for (int ks = 0; ks < 5; ++ks) {
      const int p = ks & 1;
      short8 ah = *(const short8*)&smem_hs[hiC + jl * LDK + ks * 32 + quad * 8];
      short8 al = *(const short8*)&smem_hs[loC + jl * LDK + ks * 32 + quad * 8];
      aR[p] = __builtin_amdgcn_mfma_f32_16x16x32_bf16(ah, frR[ks][0], aR[p], 0, 0, 0);
      aR[p] = __builtin_amdgcn_mfma_f32_16x16x32_bf16(ah, frR[ks][1], aR[p], 0, 0, 0);
      aR[p] = __builtin_amdgcn_mfma_f32_16x16x32_bf16(al, frR[ks][0], aR[p], 0, 0, 0);
      aZ[p] = __builtin_amdgcn_mfma_f32_16x16x32_bf16(ah, frZ[ks][0], aZ[p], 0, 0, 0);
      aZ[p] = __builtin_amdgcn_mfma_f32_16x16x32_bf16(ah, frZ[ks][1], aZ[p], 0, 0, 0);
      aZ[p] = __builtin_amdgcn_mfma_f32_16x16x32_bf16(al, frZ[ks][0], aZ[p], 0, 0, 0);
      if (ks < 4) {
        aHN[p] = __builtin_amdgcn_mfma_f32_16x16x32_bf16(ah, frN[ks][0], aHN[p], 0, 0, 0);
        aHN[p] = __builtin_amdgcn_mfma_f32_16x16x32_bf16(ah, frN[ks][1], aHN[p], 0, 0, 0);
        aHN[p] = __builtin_amdgcn_mfma_f32_16x16x32_bf16(al, frN[ks][0], aHN[p], 0, 0, 0);
      } else {
        aXN = __builtin_amdgcn_mfma_f32_16x16x32_bf16(ah, frN[4][0], aXN, 0, 0, 0);
        aXN = __builtin_amdgcn_mfma_f32_16x16x32_bf16(ah, frN[4][1], aXN, 0, 0, 0);
        aXN = __builtin_amdgcn_mfma_f32_16x16x32_bf16(al, frN[4][0], aXN, 0, 0, 0);
      }
    }

#pragma unroll
    for (int reg = 0; reg < 4; ++reg) {
      float r = sigmoidf_(aR[0][reg] + aR[1][reg] + cr);
      float z = sigmoidf_(aZ[0][reg] + aZ[1][reg] + cz);
      float n = tanhf_(aXN[reg] + cnx + r * (aHN[0][reg] + aHN[1][reg] + cnh));
      float h = (1.f - z) * n + z * hp[reg];
      hp[reg] = h;
      int s = quad * 4 + reg;
      ushort_t hb = bf16_rne(h);
      smem_hs[hiN + s * LDK + j0 + jl] = hb;
      smem_hs[loN + s * LDK + j0 + jl] = bf16_rne(h - bf16_to_f(hb));
    }
    if (tid < 256 && t < Wn - 1) {
      int s = tid >> 4, f = tid & 15;
      ushort_t hb = bf16_rne(xpre);
      smem_hs[hiN + s * LDK + 128 + f] = hb;
      smem_hs[loN + s * LDK + 128 + f] = bf16_rne(xpre - bf16_to_f(hb));
    }
    __syncthreads();
  }

  float* hs_f = (float*)smem_hs;
#pragma unroll
  for (int reg = 0; reg < 4; ++reg) {
    int s = quad * 4 + reg;
    float h = hp[reg];
    last_hid[(long)(blk * 16 + s) * Hn + j0 + jl] = h;
    hs_f[s * 132 + j0 + jl] = h;
  }
  __syncthreads();
  {
    int k = tid & 63;
    int part = (tid >> 6) & 1;
    int sg = tid >> 7;
    const float* Wp = part ? W2 : W1;
    float a[4];
    float init = part ? 0.f : b1[k];
    a[0] = a[1] = a[2] = a[3] = init;
    for (int h = 0; h < 128; h += 4) {
      float4 w = *(const float4*)&Wp[k * 128 + h];
#pragma unroll
      for (int rr = 0; rr < 4; ++rr) {
        float4 q = *(const float4*)&hs_f[(sg * 4 + rr) * 132 + h];
        a[rr] += q.x * w.x + q.y * w.y + q.z * w.z + q.w * w.w;
      }
    }
    float* outp = part ? p2 : p1;
#pragma unroll
    for (int rr = 0; rr < 4; ++rr)
      outp[(long)(blk * 16 + sg * 4 + rr) * 64 + k] = a[rr];
  }
}

// ============ mid: conv_t1 + 64x64-tile amx (factored exp) + WbT =============
__global__ __launch_bounds__(256, 2) void mid_kernel(
    const float* __restrict__ X, const float* __restrict__ conv_w,
    const float* __restrict__ conv_b, const float* __restrict__ convl_w,
    const float* __restrict__ convl_b, const float* __restrict__ gc1_W,
    const float* __restrict__ p1, const float* __restrict__ p2,
    const float* __restrict__ V, const float* __restrict__ bv,
    const float* __restrict__ Wb, ushort_t* __restrict__ t1T_hi,
    ushort_t* __restrict__ t1T_lo, ushort_t* __restrict__ WbT_hi,
    ushort_t* __restrict__ WbT_lo, float* __restrict__ amx,
    float* __restrict__ ssq) {
  int tid = threadIdx.x, blk = blockIdx.x;
  __shared__ __align__(16) char sm[73984];

  // ---- phase A: conv + t1 (8 nodes/block over 512 blocks) ----
  {
    float* xs  = (float*)sm;            // 2560 f
    float* cw  = (float*)(sm + 10240);  // 3200 f
    float* clw = (float*)(sm + 23040);  // 1600 f
    float* rs  = (float*)(sm + 29440);  // 8 x 32 f
    int n0 = blk * 8, b = n0 >> 9, m0 = n0 & 511;
    for (int idx = tid; idx < 3200; idx += 256) cw[idx] = conv_w[idx];
    for (int idx = tid; idx < 1600; idx += 256) clw[idx] = convl_w[idx];
    if (tid < 128) {
      for (int w = 0; w < 20; ++w)
        xs[tid * 20 + w] = X[((long)(b * 20 + w) * 512 + m0) * 16 + tid];
    }
    __syncthreads();
    if (tid < 80) {
      int s = tid / 10, k = tid % 10;
      float a0 = conv_b[k];
      float l0 = convl_b[k], l1 = convl_b[k];
      for (int f = 0; f < 16; ++f) {
        const float* xp = &xs[(s * 16 + f) * 20];
#pragma unroll
        for (int w = 0; w < 20; ++w) a0 = fmaf(xp[w], cw[k * 320 + f * 20 + w], a0);
#pragma unroll
        for (int q = 0; q < 10; ++q) {
          float wv = clw[k * 160 + f * 10 + q];
          l0 = fmaf(xp[2 * q], wv, l0);
          l1 = fmaf(xp[2 * q + 1], wv, l1);
        }
      }
      rs[s * 32 + k * 3 + 0] = reluf_(a0);
      rs[s * 32 + k * 3 + 1] = reluf_(l0);
      rs[s * 32 + k * 3 + 2] = reluf_(l1);
    }
    __syncthreads();
    if (tid < 128) {
      float w[30];
#pragma unroll
      for (int q = 0; q < 30; ++q) w[q] = gc1_W[q * 128 + tid];
      long base = ((long)b * 128 + tid) * 512 + m0;
#pragma unroll
      for (int s = 0; s < 8; ++s) {
        float a = 0.f;
#pragma unroll
        for (int q = 0; q < 30; ++q) a = fmaf(rs[s * 32 + q], w[q], a);
        ushort_t hb = bf16_rne(a);
        t1T_hi[base + s] = hb;
        t1T_lo[base + s] = bf16_rne(a - bf16_to_f(hb));
      }
    }
  }
  __syncthreads();

  // ---- phase B: amx 64x64 tile per block; exp factored out of inner loop ----
  {
    float* p1s  = (float*)sm;            // 64 x 68
    float* e1s  = (float*)(sm + 17408);  // 64 x 68
    float* p2s  = (float*)(sm + 34816);  // 64 x 68
    float* e2s  = (float*)(sm + 52224);  // 64 x 68
    float* cred = (float*)(sm + 69632);  // 16 x 68
    float4 vreg[16];
#pragma unroll
    for (int q = 0; q < 16; ++q) vreg[q] = *(const float4*)&V[q * 4];
    float bvv = bv[0];
    int bz = blk >> 6, i0 = ((blk >> 3) & 7) * 64, j0 = (blk & 7) * 64;
    int r0 = tid >> 4, c0 = tid & 15;

#pragma unroll
    for (int l = 0; l < 4; ++l) {
      int e = l * 1024 + tid * 4;
      int r = e >> 6, c = e & 63;
      float4 v1 = *(const float4*)&p1[(long)(bz * 512 + j0 + r) * 64 + c];
      float4 v2 = *(const float4*)&p2[(long)(bz * 512 + i0 + r) * 64 + c];
      *(float4*)&p1s[r * 68 + c] = v1;
      *(float4*)&p2s[r * 68 + c] = v2;
      float4 x1, x2;
      x1.x = __expf(v1.x); x1.y = __expf(v1.y); x1.z = __expf(v1.z); x1.w = __expf(v1.w);
      x2.x = __expf(v2.x); x2.y = __expf(v2.y); x2.z = __expf(v2.z); x2.w = __expf(v2.w);
      *(float4*)&e1s[r * 68 + c] = x1;
      *(float4*)&e2s[r * 68 + c] = x2;
    }
    __syncthreads();

    float acc[4][4] = {};
    for (int kq = 0; kq < 16; ++kq) {
      float4 pa[4], pb[4], ea[4], eb[4];
#pragma unroll
      for (int q = 0; q < 4; ++q) {
        pa[q] = *(const float4*)&p1s[(c0 + q * 16) * 68 + kq * 4];
        ea[q] = *(const float4*)&e1s[(c0 + q * 16) * 68 + kq * 4];
        pb[q] = *(const float4*)&p2s[(r0 + q * 16) * 68 + kq * 4];
        eb[q] = *(const float4*)&e2s[(r0 + q * 16) * 68 + kq * 4];
      }
      float4 vv = vreg[kq];
#pragma unroll
      for (int ri = 0; ri < 4; ++ri)
#pragma unroll
        for (int ci = 0; ci < 4; ++ci) {
          float s0 = pa[ci].x + pb[ri].x;
          float m0v = fmaf(ea[ci].x, eb[ri].x, -1.f);
          acc[ri][ci] = fmaf(s0 > 0.f ? s0 : m0v, vv.x, acc[ri][ci]);
          float s1 = pa[ci].y + pb[ri].y;
          float m1v = fmaf(ea[ci].y, eb[ri].y, -1.f);
          acc[ri][ci] = fmaf(s1 > 0.f ? s1 : m1v, vv.y, acc[ri][ci]);
          float s2v = pa[ci].z + pb[ri].z;
          float m2v = fmaf(ea[ci].z, eb[ri].z, -1.f);
          acc[ri][ci] = fmaf(s2v > 0.f ? s2v : m2v, vv.z, acc[ri][ci]);
          float s3 = pa[ci].w + pb[ri].w;
          float m3v = fmaf(ea[ci].w, eb[ri].w, -1.f);
          acc[ri][ci] = fmaf(s3 > 0.f ? s3 : m3v, vv.w, acc[ri][ci]);
        }
    }
    __syncthreads();
    float* outs = p1s;
    float s2[4] = {0.f, 0.f, 0.f, 0.f};
#pragma unroll
    for (int ri = 0; ri < 4; ++ri)
#pragma unroll
      for (int ci = 0; ci < 4; ++ci) {
        float v = acc[ri][ci] + bvv;
        outs[(r0 + ri * 16) * 68 + c0 + ci * 16] = v;
        s2[ci] += v * v;
      }
#pragma unroll
    for (int ci = 0; ci < 4; ++ci) cred[r0 * 68 + c0 + ci * 16] = s2[ci];
    __syncthreads();
#pragma unroll
    for (int l = 0; l < 4; ++l) {
      int e = l * 1024 + tid * 4;
      int r = e >> 6, c = e & 63;
      *(float4*)&amx[((long)(bz * 512 + i0 + r)) * 512 + j0 + c] =
          *(const float4*)&outs[r * 68 + c];
    }
    if (tid < 64) {
      float s = 0.f;
#pragma unroll
      for (int p = 0; p < 16; ++p) s += cred[p * 68 + tid];
      atomicAdd(&ssq[bz * 512 + j0 + tid], s);
    }
  }

  // ---- phase C: WbT transpose+split (blocks 0..63) ----
  if (blk < 64) {
    __syncthreads();
    float* wt = (float*)sm;   // 64 x 65
    int k0 = (blk >> 3) * 64, j0w = (blk & 7) * 64;
    for (int idx = tid; idx < 4096; idx += 256) {
      int r = idx >> 6, c = idx & 63;
      wt[r * 65 + c] = Wb[(long)(k0 + r) * 512 + j0w + c];
    }
    __syncthreads();
    for (int idx = tid; idx < 4096; idx += 256) {
      int r = idx >> 6, c = idx & 63;
      float v = wt[c * 65 + r];
      ushort_t hb = bf16_rne(v);
      WbT_hi[(long)(j0w + r) * 512 + k0 + c] = hb;
      WbT_lo[(long)(j0w + r) * 512 + k0 + c] = bf16_rne(v - bf16_to_f(hb));
    }
  }
}

// ---- gemm_cA via split-bf16 MFMA: 64x64 tiles, 512 blocks x 4 waves ----
#define CPK 40
__global__ __launch_bounds__(256, 2) void gemm_cA(
    const float* __restrict__ amx, const ushort_t* __restrict__ WbT_hi,
    const ushort_t* __restrict__ WbT_lo, const float* __restrict__ adj,
    const float* __restrict__ wb, const float* __restrict__ ssq,
    float* __restrict__ A) {
  const int bz = blockIdx.z;
  const int i0 = blockIdx.y * 64;
  const int j0 = blockIdx.x * 64;
  const int tid = threadIdx.x;
  const int wave = tid >> 6;
  const int lane = tid & 63;
  const int quad = lane >> 4, jl = lane & 15;
  const int wm = (wave & 1) * 32, wn = (wave >> 1) * 32;

  __shared__ __align__(16) ushort_t Ahi[64][CPK];
  __shared__ __align__(16) ushort_t Alo[64][CPK];
  __shared__ __align__(16) ushort_t Bhi[64][CPK];
  __shared__ __align__(16) ushort_t Blo[64][CPK];
  __shared__ float rs_s[512];

  const float* Abase = amx + (long)bz * 262144;
  const float* sb = ssq + bz * 512;
  for (int i = tid; i < 512; i += 256)
    rs_s[i] = __builtin_amdgcn_rcpf(fmaxf(sqrtf(sb[i]), 1e-12f));

  f32x4 acc[2][2];
#pragma unroll
  for (int a = 0; a < 2; ++a)
#pragma unroll
    for (int c = 0; c < 2; ++c) acc[a][c] = (f32x4){0.f, 0.f, 0.f, 0.f};

  for (int kk0 = 0; kk0 < 512; kk0 += 32) {
    __syncthreads();
#pragma unroll
    for (int l = 0; l < 2; ++l) {
      int e = l * 1024 + tid * 4;
      int r = e >> 5, kq = e & 31;
      float4 v = *(const float4*)&Abase[(long)(i0 + r) * 512 + kk0 + kq];
      float4 sc = *(const float4*)&rs_s[kk0 + kq];
      float vv[4] = {v.x * sc.x, v.y * sc.y, v.z * sc.z, v.w * sc.w};
#pragma unroll
      for (int q = 0; q < 4; ++q) {
        ushort_t hb = bf16_rne(vv[q]);
        Ahi[r][kq + q] = hb;
        Alo[r][kq + q] = bf16_rne(vv[q] - bf16_to_f(hb));
      }
    }
    {
      int r = tid >> 2, kc = (tid & 3) * 8;
      *(uint4*)&Bhi[r][kc] = *(const uint4*)&WbT_hi[(long)(j0 + r) * 512 + kk0 + kc];
      *(uint4*)&Blo[r][kc] = *(const uint4*)&WbT_lo[(long)(j0 + r) * 512 + kk0 + kc];
    }
    __syncthreads();
    short8 ah[2], al[2], bh[2], bl[2];
#pragma unroll
    for (int tm = 0; tm < 2; ++tm) {
      ah[tm] = *(const short8*)&Ahi[wm + tm * 16 + jl][quad * 8];
      al[tm] = *(const short8*)&Alo[wm + tm * 16 + jl][quad * 8];
    }
#pragma unroll
    for (int tn = 0; tn < 2; ++tn) {
      bh[tn] = *(const short8*)&Bhi[wn + tn * 16 + jl][quad * 8];
      bl[tn] = *(const short8*)&Blo[wn + tn * 16 + jl][quad * 8];
    }
#pragma unroll
    for (int tm = 0; tm < 2; ++tm)
#pragma unroll
      for (int tn = 0; tn < 2; ++tn) {
        acc[tm][tn] = __builtin_amdgcn_mfma_f32_16x16x32_bf16(ah[tm], bh[tn], acc[tm][tn], 0, 0, 0);
        acc[tm][tn] = __builtin_amdgcn_mfma_f32_16x16x32_bf16(ah[tm], bl[tn], acc[tm][tn], 0, 0, 0);
        acc[tm][tn] = __builtin_amdgcn_mfma_f32_16x16x32_bf16(al[tm], bh[tn], acc[tm][tn], 0, 0, 0);
      }
  }

  const float wbv = wb[0];
#pragma unroll
  for (int tn = 0; tn < 2; ++tn) {
    int j = j0 + wn + tn * 16 + jl;
    float sj = rs_s[j];
#pragma unroll
    for (int tm = 0; tm < 2; ++tm) {
#pragma unroll
      for (int reg = 0; reg < 4; ++reg) {
        int i = i0 + wm + tm * 16 + quad * 4 + reg;
        long ofs = (long)bz * 262144 + (long)i * 512 + j;
        float c = sigmoidf_(acc[tm][tn][reg] + wbv);
        float am = Abase[(long)i * 512 + j] * sj;
        float ad = adj[(long)i * 512 + j];
        A[ofs] = ad * c + am * (1.f - c);
      }
    }
  }
}

// ---------------- gemm_h1 + fused t2: 512 threads, 8 waves ----
__global__ __launch_bounds__(512, 1) void gemm_h1t2(
    const float* __restrict__ A, const ushort_t* __restrict__ t1T_hi,
    const ushort_t* __restrict__ t1T_lo, const float* __restrict__ gc1_b,
    const float* __restrict__ gc2_W, float* __restrict__ t2) {
  const int bz = blockIdx.y;
  const int i0 = blockIdx.x * 16;
  const int tid = threadIdx.x;
  const int wave = tid >> 6;
  const int lane = tid & 63;
  const int quad = lane >> 4, jl = lane & 15;

  __shared__ __align__(16) ushort_t Ahi[16][CPK];
  __shared__ __align__(16) ushort_t Alo[16][CPK];
  __shared__ __align__(16) ushort_t Bhi[128][CPK];
  __shared__ __align__(16) ushort_t Blo[128][CPK];
  __shared__ float h1s[16][132];
  __shared__ float gw[1280];

  const float* Ab = A + (long)bz * 262144;
  for (int idx = tid; idx < 1280; idx += 512) gw[idx] = gc2_W[idx];

  f32x4 acc = {0.f, 0.f, 0.f, 0.f};

  for (int kk0 = 0; kk0 < 512; kk0 += 32) {
    __syncthreads();
    {
      int r = tid >> 5, kq = tid & 31;
      float v = Ab[(long)(i0 + r) * 512 + kk0 + kq];
      ushort_t hb = bf16_rne(v);
      Ahi[r][kq] = hb;
      Alo[r][kq] = bf16_rne(v - bf16_to_f(hb));
    }
    {
      int r = tid >> 2, kc = (tid & 3) * 8;
      *(uint4*)&Bhi[r][kc] = *(const uint4*)&t1T_hi[((long)bz * 128 + r) * 512 + kk0 + kc];
      *(uint4*)&Blo[r][kc] = *(const uint4*)&t1T_lo[((long)bz * 128 + r) * 512 + kk0 + kc];
    }
    __syncthreads();
    short8 ah = *(const short8*)&Ahi[jl][quad * 8];
    short8 al = *(const short8*)&Alo[jl][quad * 8];
    short8 bh = *(const short8*)&Bhi[wave * 16 + jl][quad * 8];
    short8 bl = *(const short8*)&Blo[wave * 16 + jl][quad * 8];
    acc = __builtin_amdgcn_mfma_f32_16x16x32_bf16(ah, bh, acc, 0, 0, 0);
    acc = __builtin_amdgcn_mfma_f32_16x16x32_bf16(ah, bl, acc, 0, 0, 0);
    acc = __builtin_amdgcn_mfma_f32_16x16x32_bf16(al, bh, acc, 0, 0, 0);
  }
  __syncthreads();
  {
    int n = wave * 16 + jl;
    float bb = gc1_b[n];
#pragma unroll
    for (int reg = 0; reg < 4; ++reg) {
      int r = quad * 4 + reg;
      h1s[r][n] = reluf_(acc[reg] + bb);
    }
  }
  __syncthreads();
  if (tid < 160) {
    int r = tid / 10, c = tid % 10;
    float a = 0.f;
#pragma unroll 4
    for (int k = 0; k < 128; ++k) a = fmaf(h1s[r][k], gw[k * 10 + c], a);
    t2[((long)bz * 512 + i0 + r) * 10 + c] = a;
  }
}

// ---------------- spat+readout: BM=8, 512 blocks ----
__global__ __launch_bounds__(256) void spat_readout(
    const float* __restrict__ A, const float* __restrict__ t2,
    const float* __restrict__ gc2_b, const float* __restrict__ last_hid,
    const float* __restrict__ out_W, const float* __restrict__ out_b,
    const float* __restrict__ Y, float* __restrict__ d_out) {
  int tid = threadIdx.x;
  int bz = blockIdx.y;
  int i0 = blockIdx.x * 8;
  __shared__ float t2s[5120];
  __shared__ float wS[138];
  __shared__ float osps[8][12];
  for (int idx = tid; idx < 5120; idx += 256) t2s[idx] = t2[(long)bz * 5120 + idx];
  for (int idx = tid; idx < 138; idx += 256) wS[idx] = out_W[idx];
  __syncthreads();
  int r = tid >> 5, sk = tid & 31;
  const float* Arow = A + (long)bz * 262144 + (long)(i0 + r) * 512;
  float acc[10] = {0, 0, 0, 0, 0, 0, 0, 0, 0, 0};
  for (int k = sk; k < 512; k += 32) {
    float av = Arow[k];
    const float* tp = &t2s[k * 10];
#pragma unroll
    for (int c = 0; c < 10; ++c) acc[c] = fmaf(av, tp[c], acc[c]);
  }
#pragma unroll
  for (int off = 16; off; off >>= 1)
#pragma unroll
    for (int c = 0; c < 10; ++c) acc[c] += __shfl_xor(acc[c], off);
  if (sk == 0) {
#pragma unroll
    for (int c = 0; c < 10; ++c) osps[r][c] = reluf_(acc[c] + gc2_b[c]);
  }
  __syncthreads();
  float l = 0.f;
  if (tid < 8) {
    int gid = bz * 512 + i0 + tid;
    float y = out_b[0];
#pragma unroll
    for (int k = 0; k < 10; ++k) y = fmaf(osps[tid][k], wS[k], y);
    const float* hp = &last_hid[(long)gid * 128];
    for (int h = 0; h < 128; h += 4) {
      float4 hv = *(const float4*)&hp[h];
      y = fmaf(hv.x, wS[10 + h + 0], y);
      y = fmaf(hv.y, wS[10 + h + 1], y);
      y = fmaf(hv.z, wS[10 + h + 2], y);
      y = fmaf(hv.w, wS[10 + h + 3], y);
    }
    d_out[1 + gid] = sigmoidf_(y);
    l = fmaxf(y, 0.f) + log1pf(__expf(-fabsf(y))) - Y[gid] * y;
  }
  if (tid < 64) {
#pragma unroll
    for (int off = 4; off; off >>= 1) l += __shfl_down(l, off);
    if (tid == 0) atomicAdd(d_out, l * (1.0f / 4096.f));
  }
}

// ---------------- launcher (5 dispatches) ----------------
extern "C" void kernel_launch(void* const* d_in, const int* in_sizes, int n_in,
                              void* d_out, int out_size, void* d_ws, size_t ws_size,
                              hipStream_t stream) {
  const float* X       = (const float*)d_in[0];
  const float* Y       = (const float*)d_in[1];
  const float* adj     = (const float*)d_in[2];
  const float* V       = (const float*)d_in[3];
  const float* bv      = (const float*)d_in[4];
  const float* W1      = (const float*)d_in[5];
  const float* b1      = (const float*)d_in[6];
  const float* W2      = (const float*)d_in[7];
  const float* Wb      = (const float*)d_in[8];
  const float* wb      = (const float*)d_in[9];
  const float* conv_w  = (const float*)d_in[10];
  const float* conv_b  = (const float*)d_in[11];
  const float* convl_w = (const float*)d_in[12];
  const float* convl_b = (const float*)d_in[13];
  const float* gWih    = (const float*)d_in[14];
  const float* gWhh    = (const float*)d_in[15];
  const float* gbih    = (const float*)d_in[16];
  const float* gbhh    = (const float*)d_in[17];
  const float* gc1_W   = (const float*)d_in[18];
  const float* gc1_b   = (const float*)d_in[19];
  const float* gc2_W   = (const float*)d_in[20];
  const float* gc2_b   = (const float*)d_in[21];
  const float* out_W   = (const float*)d_in[22];
  const float* out_b   = (const float*)d_in[23];
  float* out = (float*)d_out;

  float* ws = (float*)d_ws;
  float* lhid  = ws; ws += 524288;
  float* p1    = ws; ws += 262144;
  float* p2    = ws; ws += 262144;
  float* amx   = ws; ws += 2097152;
  float* ssq   = ws; ws += 4096;
  float* Abuf  = ws; ws += 2097152;
  float* t2    = ws; ws += 40960;
  float* WbTf  = ws; ws += 262144;   // 2 x 262144 ushorts
  float* t1Tf  = ws; ws += 524288;   // 2 x 524288 ushorts
  if (ws_size < (size_t)(ws - (float*)d_ws) * sizeof(float)) return;
  ushort_t* WbT_hi = (ushort_t*)WbTf;
  ushort_t* WbT_lo = WbT_hi + 262144;
  ushort_t* t1T_hi = (ushort_t*)t1Tf;
  ushort_t* t1T_lo = t1T_hi + 524288;

  gru_kernel<<<256, 512, 0, stream>>>(X, gWhh, gWih, gbih, gbhh, W1, W2, b1,
                                      lhid, p1, p2, ssq, out);
  mid_kernel<<<512, 256, 0, stream>>>(X, conv_w, conv_b, convl_w, convl_b,
                                      gc1_W, p1, p2, V, bv, Wb,
                                      t1T_hi, t1T_lo, WbT_hi, WbT_lo, amx, ssq);
  gemm_cA<<<dim3(8, 8, 8), 256, 0, stream>>>(amx, WbT_hi, WbT_lo, adj, wb,
                                             ssq, Abuf);
  gemm_h1t2<<<dim3(32, 8), 512, 0, stream>>>(Abuf, t1T_hi, t1T_lo, gc1_b,
                                             gc2_W, t2);
  spat_readout<<<dim3(64, 8), 256, 0, stream>>>(Abuf, t2, gc2_b, lhid,
                                                out_W, out_b, Y, out);
}